// Round 2
// baseline (2946.549 us; speedup 1.0000x reference)
//
#include <hip/hip_runtime.h>

// 2-layer LSTM (B=256, T=1024, H=256, IN=1) inference; out = h_n[2,256,256], c_n[2,256,256] f32.
//
// v2: 16 clusters (16 batch rows) x 8 WGs (512 thr, 8 waves). Each wave owns 16 gate-cols of
// Whh0/Wih1/Whh1 as register-resident MFMA B-fragments. Combined step s: layer0 state t=s and
// layer1 state t=s-1 (skew 1). Cross-WG h exchange via SELF-VALIDATING u64 chunks: 4 bf16 h
// (|h|<1 => bit14 of each bf16 is always 0) + 4-bit step tag embedded in the four bit-14 slots.
// One relaxed agent-scope u64 load both detects readiness and delivers data (1 LLC round trip).
// Double-buffered by tag parity; WG-collective validation + 2 barriers/step give the overwrite
// safety induction. Harness 0xAA poison decodes to tag 0 (never a live tag) -> no ws init needed.

#define TSTEPS 1024u

typedef __attribute__((ext_vector_type(8))) short bf16x8;
typedef __attribute__((ext_vector_type(4))) float f32x4;

__device__ __forceinline__ unsigned short f2bf(float f) {
  unsigned u = __float_as_uint(f);
  u += 0x7FFFu + ((u >> 16) & 1u);   // RNE
  return (unsigned short)(u >> 16);
}
__device__ __forceinline__ float sigm(float x) { return 1.0f / (1.0f + __expf(-x)); }
__device__ __forceinline__ float tanh_f(float x) {
  float xc = fminf(fmaxf(x, -15.0f), 15.0f);
  float e = __expf(2.0f * xc);
  return (e - 1.0f) / (e + 1.0f);
}

__global__ __launch_bounds__(512, 1) void lstm2_v2(
    const float* __restrict__ x,     // [256][1024]
    const float* __restrict__ Wih0,  // [1024][1]
    const float* __restrict__ Whh0,  // [1024][256]
    const float* __restrict__ bih0, const float* __restrict__ bhh0,
    const float* __restrict__ Wih1,  // [1024][256]
    const float* __restrict__ Whh1,  // [1024][256]
    const float* __restrict__ bih1, const float* __restrict__ bhh1,
    float* __restrict__ out,                      // [4][256][256]
    unsigned long long* __restrict__ chunks)      // [2 slots][16 c][2 L][16 row][64 q] u64 = 512KB
{
  const int bid  = blockIdx.x;   // 128 WGs
  const int c    = bid & 15;     // cluster (batch group of 16 rows)
  const int iw   = bid >> 4;     // 0..7: j-block of 32 hidden cols
  const int tid  = threadIdx.x;
  const int lane = tid & 63;
  const int w    = tid >> 6;     // wave 0..7
  const int g    = w & 3;        // gate (i,f,g,o)
  const int jsub = w >> 2;       // 0..1: which 16-col half of the 32-col j-block
  const int rowE = tid >> 5;     // elementwise: local batch row 0..15
  const int jlE  = tid & 31;     // elementwise: local j 0..31

  // ---- register-resident weight B-fragments (bf16)
  bf16x8 w0[8], wi1[8], wh1[8];
  {
    const int bcol = (g << 8) + (iw << 5) + (jsub << 4) + (lane & 15);  // row of W[4H,H]
    const int kb   = (lane >> 4) << 3;
#pragma unroll
    for (int kk = 0; kk < 8; ++kk) {
      const int k0 = kk * 32 + kb;
      const float* p0 = Whh0 + (size_t)bcol * 256 + k0;
      const float* p1 = Wih1 + (size_t)bcol * 256 + k0;
      const float* p2 = Whh1 + (size_t)bcol * 256 + k0;
      bf16x8 a, b, cc;
#pragma unroll
      for (int e = 0; e < 8; ++e) {
        a[e]  = (short)f2bf(p0[e]);
        b[e]  = (short)f2bf(p1[e]);
        cc[e] = (short)f2bf(p2[e]);
      }
      w0[kk] = a; wi1[kk] = b; wh1[kk] = cc;
    }
  }

  // ---- per-thread elementwise constants
  float wx[4], bs0[4], bs1[4];
#pragma unroll
  for (int q = 0; q < 4; ++q) {
    const int col = (q << 8) + (iw << 5) + jlE;
    wx[q]  = Wih0[col];
    bs0[q] = bih0[col] + bhh0[col];
    bs1[q] = bih1[col] + bhh1[col];
  }

  // ---- per-thread fetch slots: 4 chunks each (2048 chunks = 2L x 16row x 64q)
  unsigned ofs_[4], lofs_[4];
#pragma unroll
  for (int i = 0; i < 4; ++i) {
    const int n   = tid + 512 * i;
    const int L   = n >> 10;
    const int row = (n >> 6) & 15;
    const int q   = n & 63;
    ofs_[i]  = (unsigned)(((c * 2 + L) * 16 + row) * 64 + q);   // u64 index (slot-relative)
    lofs_[i] = (unsigned)((L * 16 + row) * 264 + q * 4);        // ushort index into A
  }

  __shared__ __align__(16) unsigned short A[2 * 16 * 264];  // [L][row][k], pad 264 (read conflict-free)
  __shared__ float GL[2 * 4 * 16 * 33];                     // [L][g][row][j32], pad 33

  const float* xrow = x + (size_t)((c << 4) + rowE) * TSTEPS;

  float c0 = 0.f, h0f = 0.f, c1 = 0.f, h1f = 0.f;
  bool dead = false;

  for (unsigned s = 0; s <= TSTEPS; ++s) {
    float xv = 0.f;
    if (s < TSTEPS) xv = xrow[s];

    // ---- phase 1: acquire A0 = h0[s-1], A1 = h1[s-2]
    if (s == 0) {
      for (int z = tid; z < 4224; z += 512) ((unsigned*)A)[z] = 0u;   // zero initial state
    } else {
      const unsigned t4 = s & 15u;
      unsigned long long* sbase = chunks + (size_t)(s & 1u) * 32768u;
      int pmask = 15;
      int guard = 0;
      unsigned long long vv[4];
      while (pmask && !dead) {
#pragma unroll
        for (int i = 0; i < 4; ++i)
          if (pmask & (1 << i))
            vv[i] = __hip_atomic_load(sbase + ofs_[i], __ATOMIC_RELAXED, __HIP_MEMORY_SCOPE_AGENT);
#pragma unroll
        for (int i = 0; i < 4; ++i)
          if (pmask & (1 << i)) {
            const unsigned long long v = vv[i];
            const unsigned tg = ((unsigned)(v >> 14) & 1u) | ((unsigned)(v >> 29) & 2u) |
                                ((unsigned)(v >> 44) & 4u) | ((unsigned)(v >> 59) & 8u);
            if (tg == t4) {
              *(unsigned long long*)&A[lofs_[i]] = v & 0xBFFFBFFFBFFFBFFFULL;
              pmask &= ~(1 << i);
            }
          }
        if (++guard > (1 << 14)) dead = true;   // sticky bailout: no hangs
      }
    }
    __syncthreads();   // BARRIER-A: A ready; also fences prev-step GL reads

    // ---- phase 2: MFMA  acc0 = A0@Whh0^T ; acc1 = A0@Wih1^T + A1@Whh1^T
    f32x4 acc0 = {0.f, 0.f, 0.f, 0.f};
    f32x4 acc1 = {0.f, 0.f, 0.f, 0.f};
    {
      const unsigned short* a0p = &A[(lane & 15) * 264 + ((lane >> 4) << 3)];
      const unsigned short* a1p = a0p + 16 * 264;
#pragma unroll
      for (int kk = 0; kk < 8; ++kk) {
        bf16x8 af = *(const bf16x8*)(a0p + kk * 32);
        acc0 = __builtin_amdgcn_mfma_f32_16x16x32_bf16(af, w0[kk], acc0, 0, 0, 0);
        acc1 = __builtin_amdgcn_mfma_f32_16x16x32_bf16(af, wi1[kk], acc1, 0, 0, 0);
      }
#pragma unroll
      for (int kk = 0; kk < 8; ++kk) {
        bf16x8 af = *(const bf16x8*)(a1p + kk * 32);
        acc1 = __builtin_amdgcn_mfma_f32_16x16x32_bf16(af, wh1[kk], acc1, 0, 0, 0);
      }
    }
    {
      const int dr = (lane >> 4) << 2;
      const int dc = (jsub << 4) + (lane & 15);
      float* g0 = &GL[((0 * 4 + g) * 16 + dr) * 33 + dc];
      float* g1 = &GL[((1 * 4 + g) * 16 + dr) * 33 + dc];
#pragma unroll
      for (int r = 0; r < 4; ++r) { g0[r * 33] = acc0[r]; g1[r * 33] = acc1[r]; }
    }
    __syncthreads();   // BARRIER-B: GL ready; also fences A reads vs next-step A writes

    // ---- phase 3: elementwise cell updates + publish
    if (s < TSTEPS) {
      const float pi = GL[((0 * 4 + 0) * 16 + rowE) * 33 + jlE] + xv * wx[0] + bs0[0];
      const float pf = GL[((0 * 4 + 1) * 16 + rowE) * 33 + jlE] + xv * wx[1] + bs0[1];
      const float pg = GL[((0 * 4 + 2) * 16 + rowE) * 33 + jlE] + xv * wx[2] + bs0[2];
      const float po = GL[((0 * 4 + 3) * 16 + rowE) * 33 + jlE] + xv * wx[3] + bs0[3];
      const float ig = sigm(pi), fg = sigm(pf), gv = tanh_f(pg), og = sigm(po);
      c0  = fg * c0 + ig * gv;
      h0f = og * tanh_f(c0);
    }
    if (s >= 1u) {
      const float pi = GL[((1 * 4 + 0) * 16 + rowE) * 33 + jlE] + bs1[0];
      const float pf = GL[((1 * 4 + 1) * 16 + rowE) * 33 + jlE] + bs1[1];
      const float pg = GL[((1 * 4 + 2) * 16 + rowE) * 33 + jlE] + bs1[2];
      const float po = GL[((1 * 4 + 3) * 16 + rowE) * 33 + jlE] + bs1[3];
      const float ig = sigm(pi), fg = sigm(pf), gv = tanh_f(pg), og = sigm(po);
      c1  = fg * c1 + ig * gv;
      h1f = og * tanh_f(c1);
    }

    if (s < TSTEPS) {
      const unsigned tau = s + 1u;
      const unsigned long long tmask =
          ((unsigned long long)(tau & 1u)        << 14) |
          ((unsigned long long)((tau >> 1) & 1u) << 30) |
          ((unsigned long long)((tau >> 2) & 1u) << 46) |
          ((unsigned long long)((tau >> 3) & 1u) << 62);
      const int p0 = (int)(unsigned)f2bf(h0f);
      const int p1 = (int)(unsigned)f2bf(h1f);
      const int a1v = __shfl_down(p0, 1), a2v = __shfl_down(p0, 2), a3v = __shfl_down(p0, 3);
      const int b1v = __shfl_down(p1, 1), b2v = __shfl_down(p1, 2), b3v = __shfl_down(p1, 3);
      if ((jlE & 3) == 0) {
        unsigned long long* pb = chunks + (size_t)(tau & 1u) * 32768u;
        const int q = (iw << 3) + (jlE >> 2);
        unsigned long long v0 = (unsigned long long)(unsigned)p0 |
                                ((unsigned long long)(unsigned)a1v << 16) |
                                ((unsigned long long)(unsigned)a2v << 32) |
                                ((unsigned long long)(unsigned)a3v << 48);
        v0 = (v0 & 0xBFFFBFFFBFFFBFFFULL) | tmask;
        __hip_atomic_store(pb + ((c * 2 + 0) * 16 + rowE) * 64 + q, v0,
                           __ATOMIC_RELAXED, __HIP_MEMORY_SCOPE_AGENT);
        unsigned long long v1 = (unsigned long long)(unsigned)p1 |
                                ((unsigned long long)(unsigned)b1v << 16) |
                                ((unsigned long long)(unsigned)b2v << 32) |
                                ((unsigned long long)(unsigned)b3v << 48);
        v1 = (v1 & 0xBFFFBFFFBFFFBFFFULL) | tmask;
        __hip_atomic_store(pb + ((c * 2 + 1) * 16 + rowE) * 64 + q, v1,
                           __ATOMIC_RELAXED, __HIP_MEMORY_SCOPE_AGENT);
      }
    }
  }

  // ---- epilogue
  {
    const int b  = (c << 4) + rowE;
    const int jg = (iw << 5) + jlE;
    const size_t o = (size_t)b * 256 + jg;
    out[o]                  = h0f;   // h_n layer 0  (h0[1023])
    out[65536 + o]          = h1f;   // h_n layer 1  (h1[1023])
    out[131072 + o]         = c0;    // c_n layer 0
    out[131072 + 65536 + o] = c1;    // c_n layer 1
  }
}

extern "C" void kernel_launch(void* const* d_in, const int* in_sizes, int n_in,
                              void* d_out, int out_size, void* d_ws, size_t ws_size,
                              hipStream_t stream) {
  const float* x    = (const float*)d_in[0];
  const float* Wih0 = (const float*)d_in[1];
  const float* Whh0 = (const float*)d_in[2];
  const float* bih0 = (const float*)d_in[3];
  const float* bhh0 = (const float*)d_in[4];
  const float* Wih1 = (const float*)d_in[5];
  const float* Whh1 = (const float*)d_in[6];
  const float* bih1 = (const float*)d_in[7];
  const float* bhh1 = (const float*)d_in[8];

  // No ws init needed: 0xAA poison decodes to tag 0, which never matches a live tag (1..1024 mod 16
  // only aliases 0 at tags 16,32,... by which time real data has long overwritten the poison slots,
  // and the s=0 step reads nothing).
  lstm2_v2<<<128, 512, 0, stream>>>(x, Wih0, Whh0, bih0, bhh0,
                                    Wih1, Whh1, bih1, bhh1,
                                    (float*)d_out, (unsigned long long*)d_ws);
}

// Round 3
// 2656.790 us; speedup vs baseline: 1.1091x; 1.1091x over previous
//
#include <hip/hip_runtime.h>

// 2-layer LSTM (B=256, T=1024, H=256, IN=1) inference; out = h_n[2,256,256], c_n[2,256,256] f32.
//
// v3: same decomposition as v2 (16 clusters x 8 WGs x 512 thr; register-resident weights;
// skewed layer fusion; self-validating tagged u64 chunks, double-buffered by parity).
// NEW: exchange is dual-published:
//   FAST path: WORKGROUP-scope atomic stores -> plain global_store, write-through L1, lands
//              and STAYS in the producer XCD's L2 (cluster WGs are same-XCD under round-robin
//              dispatch) -> consumer AGENT-scope loads (L1-bypass) hit updated L2 in ~200-400cy.
//   SLOW path: AGENT-scope write-through mirror (globally coherent). Consumers poll fast first
//              (384 tries), then fall back to the mirror. Placement assumption broken => v2-speed,
//              still correct. Tag-in-data (bit14 of each bf16, always 0 since |h|<1) validates
//              freshness either way; 0xAA poison decodes to tag 0 (never live at the step that
//              could read it) -> no ws init needed.

#define TSTEPS 1024u

typedef __attribute__((ext_vector_type(8))) short bf16x8;
typedef __attribute__((ext_vector_type(4))) float f32x4;

__device__ __forceinline__ unsigned short f2bf(float f) {
  unsigned u = __float_as_uint(f);
  u += 0x7FFFu + ((u >> 16) & 1u);   // RNE
  return (unsigned short)(u >> 16);
}
__device__ __forceinline__ float sigm(float x) { return 1.0f / (1.0f + __expf(-x)); }
__device__ __forceinline__ float tanh_f(float x) {
  float xc = fminf(fmaxf(x, -15.0f), 15.0f);
  float e = __expf(2.0f * xc);
  return (e - 1.0f) / (e + 1.0f);
}

__global__ __launch_bounds__(512, 1) void lstm2_v3(
    const float* __restrict__ x,     // [256][1024]
    const float* __restrict__ Wih0,  // [1024][1]
    const float* __restrict__ Whh0,  // [1024][256]
    const float* __restrict__ bih0, const float* __restrict__ bhh0,
    const float* __restrict__ Wih1,  // [1024][256]
    const float* __restrict__ Whh1,  // [1024][256]
    const float* __restrict__ bih1, const float* __restrict__ bhh1,
    float* __restrict__ out,                      // [4][256][256]
    unsigned long long* __restrict__ fastb,       // [2][16c][2L][16row][64q] u64 = 512KB (L2-local)
    unsigned long long* __restrict__ slowb)       // same layout, agent write-through mirror
{
  const int bid  = blockIdx.x;   // 128 WGs; cluster c's WGs {c, c+16, ...} -> same XCD (c%8)
  const int c    = bid & 15;
  const int iw   = bid >> 4;     // 0..7: j-block of 32 hidden cols
  const int tid  = threadIdx.x;
  const int lane = tid & 63;
  const int w    = tid >> 6;
  const int g    = w & 3;        // gate (i,f,g,o)
  const int jsub = w >> 2;       // 16-col half of the 32-col j-block
  const int rowE = tid >> 5;     // elementwise: local batch row 0..15
  const int jlE  = tid & 31;     // elementwise: local j 0..31

  const unsigned long long TB = 0x4000400040004000ULL;  // tag bit slots (bit14 of each bf16)

  // ---- register-resident weight B-fragments (bf16)
  bf16x8 w0[8], wi1[8], wh1[8];
  {
    const int bcol = (g << 8) + (iw << 5) + (jsub << 4) + (lane & 15);
    const int kb   = (lane >> 4) << 3;
#pragma unroll
    for (int kk = 0; kk < 8; ++kk) {
      const int k0 = kk * 32 + kb;
      const float* p0 = Whh0 + (size_t)bcol * 256 + k0;
      const float* p1 = Wih1 + (size_t)bcol * 256 + k0;
      const float* p2 = Whh1 + (size_t)bcol * 256 + k0;
      bf16x8 a, b, cc;
#pragma unroll
      for (int e = 0; e < 8; ++e) {
        a[e]  = (short)f2bf(p0[e]);
        b[e]  = (short)f2bf(p1[e]);
        cc[e] = (short)f2bf(p2[e]);
      }
      w0[kk] = a; wi1[kk] = b; wh1[kk] = cc;
    }
  }

  // ---- per-thread elementwise constants
  float wx[4], bs0[4], bs1[4];
#pragma unroll
  for (int q = 0; q < 4; ++q) {
    const int col = (q << 8) + (iw << 5) + jlE;
    wx[q]  = Wih0[col];
    bs0[q] = bih0[col] + bhh0[col];
    bs1[q] = bih1[col] + bhh1[col];
  }

  // ---- per-thread fetch slots: 4 chunks each
  unsigned ofs_[4], lofs_[4];
#pragma unroll
  for (int i = 0; i < 4; ++i) {
    const int n   = tid + 512 * i;
    const int L   = n >> 10;
    const int row = (n >> 6) & 15;
    const int q   = n & 63;
    ofs_[i]  = (unsigned)(((c * 2 + L) * 16 + row) * 64 + q);
    lofs_[i] = (unsigned)((L * 16 + row) * 264 + q * 4);
  }

  __shared__ __align__(16) unsigned short A[2 * 16 * 264];
  __shared__ float GL[2 * 4 * 16 * 33];

  const float* xrow = x + (size_t)((c << 4) + rowE) * TSTEPS;

  float c0 = 0.f, h0f = 0.f, c1 = 0.f, h1f = 0.f;
  bool dead = false;

  for (unsigned s = 0; s <= TSTEPS; ++s) {
    float xv = 0.f;
    if (s < TSTEPS) xv = xrow[s];   // independent; overlaps the poll

    // ---- phase 1: acquire A0 = h0[s-1], A1 = h1[s-2]
    if (s == 0) {
      for (int z = tid; z < 4224; z += 512) ((unsigned*)A)[z] = 0u;
    } else {
      const unsigned t4 = s & 15u;
      const unsigned long long em =
          ((unsigned long long)(t4 & 1u)        << 14) |
          ((unsigned long long)((t4 >> 1) & 1u) << 30) |
          ((unsigned long long)((t4 >> 2) & 1u) << 46) |
          ((unsigned long long)((t4 >> 3) & 1u) << 62);
      unsigned long long* fbase = fastb + (size_t)(s & 1u) * 32768u;
      int pmask = 15;
      {
        int guard = 0;
        unsigned long long vv[4];
        while (pmask) {                    // FAST: L2-resident chunks
#pragma unroll
          for (int i = 0; i < 4; ++i)
            if (pmask & (1 << i))
              vv[i] = __hip_atomic_load(fbase + ofs_[i], __ATOMIC_RELAXED, __HIP_MEMORY_SCOPE_AGENT);
#pragma unroll
          for (int i = 0; i < 4; ++i)
            if ((pmask & (1 << i)) && ((vv[i] & TB) == em)) {
              *(unsigned long long*)&A[lofs_[i]] = vv[i] & ~TB;
              pmask &= ~(1 << i);
            }
          if (++guard > 384) break;
        }
      }
      if (pmask) {                         // SLOW fallback: agent write-through mirror
        unsigned long long* sbase = slowb + (size_t)(s & 1u) * 32768u;
        int guard = 0;
        unsigned long long vv[4];
        while (pmask && !dead) {
#pragma unroll
          for (int i = 0; i < 4; ++i)
            if (pmask & (1 << i))
              vv[i] = __hip_atomic_load(sbase + ofs_[i], __ATOMIC_RELAXED, __HIP_MEMORY_SCOPE_AGENT);
#pragma unroll
          for (int i = 0; i < 4; ++i)
            if ((pmask & (1 << i)) && ((vv[i] & TB) == em)) {
              *(unsigned long long*)&A[lofs_[i]] = vv[i] & ~TB;
              pmask &= ~(1 << i);
            }
          if (++guard > (1 << 14)) dead = true;
        }
      }
    }
    __syncthreads();   // BARRIER-A

    // ---- phase 2: MFMA  acc0 = A0@Whh0^T ; acc1 = A0@Wih1^T + A1@Whh1^T
    f32x4 acc0 = {0.f, 0.f, 0.f, 0.f};
    f32x4 acc1 = {0.f, 0.f, 0.f, 0.f};
    {
      const unsigned short* a0p = &A[(lane & 15) * 264 + ((lane >> 4) << 3)];
      const unsigned short* a1p = a0p + 16 * 264;
#pragma unroll
      for (int kk = 0; kk < 8; ++kk) {
        bf16x8 af = *(const bf16x8*)(a0p + kk * 32);
        acc0 = __builtin_amdgcn_mfma_f32_16x16x32_bf16(af, w0[kk], acc0, 0, 0, 0);
        acc1 = __builtin_amdgcn_mfma_f32_16x16x32_bf16(af, wi1[kk], acc1, 0, 0, 0);
      }
#pragma unroll
      for (int kk = 0; kk < 8; ++kk) {
        bf16x8 af = *(const bf16x8*)(a1p + kk * 32);
        acc1 = __builtin_amdgcn_mfma_f32_16x16x32_bf16(af, wh1[kk], acc1, 0, 0, 0);
      }
    }
    {
      const int dr = (lane >> 4) << 2;
      const int dc = (jsub << 4) + (lane & 15);
      float* g0 = &GL[((0 * 4 + g) * 16 + dr) * 33 + dc];
      float* g1 = &GL[((1 * 4 + g) * 16 + dr) * 33 + dc];
#pragma unroll
      for (int r = 0; r < 4; ++r) { g0[r * 33] = acc0[r]; g1[r * 33] = acc1[r]; }
    }
    __syncthreads();   // BARRIER-B

    // ---- phase 3: elementwise + dual publish (h0 first, it's on the next step's critical path)
    const unsigned tau = s + 1u;
    const unsigned long long emn =
        ((unsigned long long)(tau & 1u)        << 14) |
        ((unsigned long long)((tau >> 1) & 1u) << 30) |
        ((unsigned long long)((tau >> 2) & 1u) << 46) |
        ((unsigned long long)((tau >> 3) & 1u) << 62);
    unsigned long long* fb = fastb + (size_t)(tau & 1u) * 32768u;
    unsigned long long* sb = slowb + (size_t)(tau & 1u) * 32768u;
    const unsigned qq = (unsigned)((iw << 3) + (jlE >> 2));
    const unsigned i0 = ((c * 2 + 0) * 16 + (unsigned)rowE) * 64 + qq;
    const unsigned i1 = ((c * 2 + 1) * 16 + (unsigned)rowE) * 64 + qq;
    const int lb = lane & ~3;

    if (s < TSTEPS) {
      const float pi = GL[((0 * 4 + 0) * 16 + rowE) * 33 + jlE] + xv * wx[0] + bs0[0];
      const float pf = GL[((0 * 4 + 1) * 16 + rowE) * 33 + jlE] + xv * wx[1] + bs0[1];
      const float pg = GL[((0 * 4 + 2) * 16 + rowE) * 33 + jlE] + xv * wx[2] + bs0[2];
      const float po = GL[((0 * 4 + 3) * 16 + rowE) * 33 + jlE] + xv * wx[3] + bs0[3];
      const float ig = sigm(pi), fg = sigm(pf), gv = tanh_f(pg), og = sigm(po);
      c0  = fg * c0 + ig * gv;
      h0f = og * tanh_f(c0);

      const int p0 = (int)(unsigned)f2bf(h0f);
      const int e0 = __shfl(p0, lb), e1 = __shfl(p0, lb + 1),
                e2 = __shfl(p0, lb + 2), e3 = __shfl(p0, lb + 3);
      unsigned long long v0 = (unsigned long long)(unsigned short)e0 |
                              ((unsigned long long)(unsigned short)e1 << 16) |
                              ((unsigned long long)(unsigned short)e2 << 32) |
                              ((unsigned long long)(unsigned short)e3 << 48);
      v0 = (v0 & ~TB) | emn;
      if ((jlE & 3) == 0)
        __hip_atomic_store(fb + i0, v0, __ATOMIC_RELAXED, __HIP_MEMORY_SCOPE_WORKGROUP);
      else if ((jlE & 3) == 1)
        __hip_atomic_store(sb + i0, v0, __ATOMIC_RELAXED, __HIP_MEMORY_SCOPE_AGENT);
    }

    if (s >= 1u) {
      const float pi = GL[((1 * 4 + 0) * 16 + rowE) * 33 + jlE] + bs1[0];
      const float pf = GL[((1 * 4 + 1) * 16 + rowE) * 33 + jlE] + bs1[1];
      const float pg = GL[((1 * 4 + 2) * 16 + rowE) * 33 + jlE] + bs1[2];
      const float po = GL[((1 * 4 + 3) * 16 + rowE) * 33 + jlE] + bs1[3];
      const float ig = sigm(pi), fg = sigm(pf), gv = tanh_f(pg), og = sigm(po);
      c1  = fg * c1 + ig * gv;
      h1f = og * tanh_f(c1);
    }

    if (s < TSTEPS) {
      const int p1 = (int)(unsigned)f2bf(h1f);
      const int e0 = __shfl(p1, lb), e1 = __shfl(p1, lb + 1),
                e2 = __shfl(p1, lb + 2), e3 = __shfl(p1, lb + 3);
      unsigned long long v1 = (unsigned long long)(unsigned short)e0 |
                              ((unsigned long long)(unsigned short)e1 << 16) |
                              ((unsigned long long)(unsigned short)e2 << 32) |
                              ((unsigned long long)(unsigned short)e3 << 48);
      v1 = (v1 & ~TB) | emn;
      if ((jlE & 3) == 0)
        __hip_atomic_store(fb + i1, v1, __ATOMIC_RELAXED, __HIP_MEMORY_SCOPE_WORKGROUP);
      else if ((jlE & 3) == 1)
        __hip_atomic_store(sb + i1, v1, __ATOMIC_RELAXED, __HIP_MEMORY_SCOPE_AGENT);
    }
  }

  // ---- epilogue
  {
    const int b  = (c << 4) + rowE;
    const int jg = (iw << 5) + jlE;
    const size_t o = (size_t)b * 256 + jg;
    out[o]                  = h0f;
    out[65536 + o]          = h1f;
    out[131072 + o]         = c0;
    out[131072 + 65536 + o] = c1;
  }
}

extern "C" void kernel_launch(void* const* d_in, const int* in_sizes, int n_in,
                              void* d_out, int out_size, void* d_ws, size_t ws_size,
                              hipStream_t stream) {
  const float* x    = (const float*)d_in[0];
  const float* Wih0 = (const float*)d_in[1];
  const float* Whh0 = (const float*)d_in[2];
  const float* bih0 = (const float*)d_in[3];
  const float* bhh0 = (const float*)d_in[4];
  const float* Wih1 = (const float*)d_in[5];
  const float* Whh1 = (const float*)d_in[6];
  const float* bih1 = (const float*)d_in[7];
  const float* bhh1 = (const float*)d_in[8];

  unsigned long long* fastb = (unsigned long long*)d_ws;
  // mirror at +512KB if the workspace allows; else alias (duplicate stores of identical bytes)
  unsigned long long* slowb = (ws_size >= (1u << 20)) ? fastb + 65536 : fastb;

  lstm2_v3<<<128, 512, 0, stream>>>(x, Wih0, Whh0, bih0, bhh0,
                                    Wih1, Whh1, bih1, bhh1,
                                    (float*)d_out, fastb, slowb);
}

// Round 4
// 2348.467 us; speedup vs baseline: 1.2547x; 1.1313x over previous
//
#include <hip/hip_runtime.h>

// 2-layer LSTM (B=256, T=1024, H=256, IN=1) inference; out = h_n[2,256,256], c_n[2,256,256] f32.
//
// v4: decomposition as v3 (16 clusters x 8 WGs x 512 thr; register-resident weight B-frags;
// skewed layer fusion; tagged self-validating u64 chunks, parity double-buffered).
// NEW: runtime XCD-placement handshake. Each WG publishes its XCC_ID (agent scope); WG0 of each
// cluster decides uniform = "all 8 WGs share an XCD" and broadcasts it (single decider -> no
// split-brain). Uniform (expected): steady-state publishes are WORKGROUP-scope plain stores --
// CDNA L1 is write-through so they land & stay dirty in the local L2; consumer sc0 loads hit L2;
// no per-step HBM write-through drain (v1-v3's shared ~1us/step cost, WRITE_SIZE=263MB evidence).
// Non-uniform: dual-publish with agent-scope mirror (slow but correct on any placement).
// Tag-in-data (bit14 of each bf16, 0 since |h|<1) validates freshness; 0xAA poison reads as
// tag 0 which is never a live tag at first use -> no ws init needed.

#define TSTEPS 1024u

typedef __attribute__((ext_vector_type(8))) short bf16x8;
typedef __attribute__((ext_vector_type(4))) float f32x4;

__device__ __forceinline__ unsigned short f2bf(float f) {
  unsigned u = __float_as_uint(f);
  u += 0x7FFFu + ((u >> 16) & 1u);   // RNE
  return (unsigned short)(u >> 16);
}
__device__ __forceinline__ float sigm(float x) { return 1.0f / (1.0f + __expf(-x)); }
__device__ __forceinline__ float tanh_f(float x) {
  float xc = fminf(fmaxf(x, -15.0f), 15.0f);
  float e = __expf(2.0f * xc);
  return (e - 1.0f) / (e + 1.0f);
}

__global__ __launch_bounds__(512, 1) void lstm2_v4(
    const float* __restrict__ x,     // [256][1024]
    const float* __restrict__ Wih0,  // [1024][1]
    const float* __restrict__ Whh0,  // [1024][256]
    const float* __restrict__ bih0, const float* __restrict__ bhh0,
    const float* __restrict__ Wih1,  // [1024][256]
    const float* __restrict__ Whh1,  // [1024][256]
    const float* __restrict__ bih1, const float* __restrict__ bhh1,
    float* __restrict__ out,                      // [4][256][256]
    unsigned long long* __restrict__ fastb,       // [2][16c][2L][16row][64q] u64 = 512KB, L2-local
    unsigned long long* __restrict__ slowb,       // same layout; agent write-through mirror
    unsigned* __restrict__ ctrl)                  // [128] xcc slots + [16] decisions
{
  const int bid  = blockIdx.x;   // 128 WGs; cluster c's WGs {c, c+16, ...}
  const int c    = bid & 15;
  const int iw   = bid >> 4;     // 0..7: j-block of 32 hidden cols
  const int tid  = threadIdx.x;
  const int lane = tid & 63;
  const int w    = tid >> 6;
  const int g    = w & 3;        // gate (i,f,g,o)
  const int jsub = w >> 2;       // 16-col half of the 32-col j-block
  const int rowE = tid >> 5;     // elementwise: local batch row 0..15
  const int jlE  = tid & 31;     // elementwise: local j 0..31

  const unsigned long long TB = 0x4000400040004000ULL;  // tag slots (bit14 of each bf16)

  // ---- publish my XCD id immediately (agent scope, globally visible)
  unsigned myxcc;
  asm volatile("s_getreg_b32 %0, hwreg(HW_REG_XCC_ID)" : "=s"(myxcc));
  myxcc &= 0xFu;
  if (tid == 0)
    __hip_atomic_store(&ctrl[(c << 3) + iw], 0x5A5A0000u | myxcc,
                       __ATOMIC_RELAXED, __HIP_MEMORY_SCOPE_AGENT);

  // ---- register-resident weight B-fragments (bf16) -- overlaps the handshake
  bf16x8 w0[8], wi1[8], wh1[8];
  {
    const int bcol = (g << 8) + (iw << 5) + (jsub << 4) + (lane & 15);
    const int kb   = (lane >> 4) << 3;
#pragma unroll
    for (int kk = 0; kk < 8; ++kk) {
      const int k0 = kk * 32 + kb;
      const float* p0 = Whh0 + (size_t)bcol * 256 + k0;
      const float* p1 = Wih1 + (size_t)bcol * 256 + k0;
      const float* p2 = Whh1 + (size_t)bcol * 256 + k0;
      bf16x8 a, b, cc;
#pragma unroll
      for (int e = 0; e < 8; ++e) {
        a[e]  = (short)f2bf(p0[e]);
        b[e]  = (short)f2bf(p1[e]);
        cc[e] = (short)f2bf(p2[e]);
      }
      w0[kk] = a; wi1[kk] = b; wh1[kk] = cc;
    }
  }

  // ---- per-thread elementwise constants
  float wx[4], bs0[4], bs1[4];
#pragma unroll
  for (int q = 0; q < 4; ++q) {
    const int col = (q << 8) + (iw << 5) + jlE;
    wx[q]  = Wih0[col];
    bs0[q] = bih0[col] + bhh0[col];
    bs1[q] = bih1[col] + bhh1[col];
  }

  // ---- per-thread fetch slots: 4 chunks each
  unsigned ofs_[4], lofs_[4];
#pragma unroll
  for (int i = 0; i < 4; ++i) {
    const int n   = tid + 512 * i;
    const int L   = n >> 10;
    const int row = (n >> 6) & 15;
    const int q   = n & 63;
    ofs_[i]  = (unsigned)(((c * 2 + L) * 16 + row) * 64 + q);
    lofs_[i] = (unsigned)((L * 16 + row) * 264 + q * 4);
  }

  // ---- handshake: WG0 decides uniformity, broadcasts; everyone adopts its decision
  __shared__ unsigned s_uni;
  if (tid == 0) {
    if (iw == 0) {
      unsigned x0 = 0, uni = 1u;
      for (int k = 0; k < 8 && uni; ++k) {
        unsigned v; int g2 = 0;
        for (;;) {
          v = __hip_atomic_load(&ctrl[(c << 3) + k], __ATOMIC_RELAXED, __HIP_MEMORY_SCOPE_AGENT);
          if ((v & 0xFFFF0000u) == 0x5A5A0000u) break;
          if (++g2 > (1 << 15)) { uni = 0u; break; }
        }
        if (uni) {
          const unsigned xc = v & 0xFFFFu;
          if (k == 0) x0 = xc; else if (xc != x0) uni = 0u;
        }
      }
      __hip_atomic_store(&ctrl[128 + c], 0x5A5A0000u | uni,
                         __ATOMIC_RELAXED, __HIP_MEMORY_SCOPE_AGENT);
    }
    unsigned uni = 0u; int g2 = 0;
    for (;;) {
      unsigned v = __hip_atomic_load(&ctrl[128 + c], __ATOMIC_RELAXED, __HIP_MEMORY_SCOPE_AGENT);
      if ((v & 0xFFFF0000u) == 0x5A5A0000u) { uni = v & 1u; break; }
      if (++g2 > (1 << 15)) break;
    }
    s_uni = uni;
  }
  __syncthreads();
  const bool uniform = (s_uni != 0u);

  __shared__ __align__(16) unsigned short A[2 * 16 * 264];
  __shared__ float GL[2 * 4 * 16 * 33];

  // consumers poll the buffer that is guaranteed visible under the decided protocol
  unsigned long long* pollb = uniform ? fastb : slowb;

  const float* xrow = x + (size_t)((c << 4) + rowE) * TSTEPS;

  float c0 = 0.f, h0f = 0.f, c1 = 0.f, h1f = 0.f;
  bool dead = false;

  for (unsigned s = 0; s <= TSTEPS; ++s) {
    float xv = 0.f;
    if (s < TSTEPS) xv = xrow[s];   // overlaps the poll

    // ---- phase 1: acquire A0 = h0[s-1], A1 = h1[s-2]
    if (s == 0) {
      for (int z = tid; z < 4224; z += 512) ((unsigned*)A)[z] = 0u;
    } else {
      const unsigned t4 = s & 15u;
      const unsigned long long em =
          ((unsigned long long)(t4 & 1u)        << 14) |
          ((unsigned long long)((t4 >> 1) & 1u) << 30) |
          ((unsigned long long)((t4 >> 2) & 1u) << 46) |
          ((unsigned long long)((t4 >> 3) & 1u) << 62);
      const unsigned long long* pb = pollb + (size_t)(s & 1u) * 32768u;
      unsigned long long vv[4] = {0, 0, 0, 0};
      int guard = 0;
      while (!dead) {
#pragma unroll
        for (int i = 0; i < 4; ++i)
          vv[i] = __hip_atomic_load(pb + ofs_[i], __ATOMIC_RELAXED, __HIP_MEMORY_SCOPE_AGENT);
        const bool ok = ((vv[0] & TB) == em) & ((vv[1] & TB) == em) &
                        ((vv[2] & TB) == em) & ((vv[3] & TB) == em);
        if (__all(ok)) break;
        if (++guard > (1 << 14)) dead = true;   // sticky bailout: terminate, fail visibly
      }
#pragma unroll
      for (int i = 0; i < 4; ++i)
        *(unsigned long long*)&A[lofs_[i]] = vv[i] & ~TB;
    }
    __syncthreads();   // BARRIER-A

    // ---- phase 2: MFMA  acc0 = A0@Whh0^T ; acc1 = A0@Wih1^T + A1@Whh1^T
    f32x4 acc0 = {0.f, 0.f, 0.f, 0.f};
    f32x4 acc1 = {0.f, 0.f, 0.f, 0.f};
    {
      const unsigned short* a0p = &A[(lane & 15) * 264 + ((lane >> 4) << 3)];
      const unsigned short* a1p = a0p + 16 * 264;
#pragma unroll
      for (int kk = 0; kk < 8; ++kk) {
        bf16x8 af = *(const bf16x8*)(a0p + kk * 32);
        acc0 = __builtin_amdgcn_mfma_f32_16x16x32_bf16(af, w0[kk], acc0, 0, 0, 0);
        acc1 = __builtin_amdgcn_mfma_f32_16x16x32_bf16(af, wi1[kk], acc1, 0, 0, 0);
      }
#pragma unroll
      for (int kk = 0; kk < 8; ++kk) {
        bf16x8 af = *(const bf16x8*)(a1p + kk * 32);
        acc1 = __builtin_amdgcn_mfma_f32_16x16x32_bf16(af, wh1[kk], acc1, 0, 0, 0);
      }
    }
    {
      const int dr = (lane >> 4) << 2;
      const int dc = (jsub << 4) + (lane & 15);
      float* g0 = &GL[((0 * 4 + g) * 16 + dr) * 33 + dc];
      float* g1 = &GL[((1 * 4 + g) * 16 + dr) * 33 + dc];
#pragma unroll
      for (int r = 0; r < 4; ++r) { g0[r * 33] = acc0[r]; g1[r * 33] = acc1[r]; }
    }
    __syncthreads();   // BARRIER-B

    // ---- phase 3: elementwise + publish (h0 first: it feeds both next-step GEMMs)
    const unsigned tau = s + 1u;
    const unsigned long long emn =
        ((unsigned long long)(tau & 1u)        << 14) |
        ((unsigned long long)((tau >> 1) & 1u) << 30) |
        ((unsigned long long)((tau >> 2) & 1u) << 46) |
        ((unsigned long long)((tau >> 3) & 1u) << 62);
    unsigned long long* fb = fastb + (size_t)(tau & 1u) * 32768u;
    unsigned long long* sb = slowb + (size_t)(tau & 1u) * 32768u;
    const unsigned qq = (unsigned)((iw << 3) + (jlE >> 2));
    const unsigned i0 = ((c * 2 + 0) * 16 + (unsigned)rowE) * 64 + qq;
    const unsigned i1 = ((c * 2 + 1) * 16 + (unsigned)rowE) * 64 + qq;
    const int lb = lane & ~3;

    if (s < TSTEPS) {
      const float pi = GL[((0 * 4 + 0) * 16 + rowE) * 33 + jlE] + xv * wx[0] + bs0[0];
      const float pf = GL[((0 * 4 + 1) * 16 + rowE) * 33 + jlE] + xv * wx[1] + bs0[1];
      const float pg = GL[((0 * 4 + 2) * 16 + rowE) * 33 + jlE] + xv * wx[2] + bs0[2];
      const float po = GL[((0 * 4 + 3) * 16 + rowE) * 33 + jlE] + xv * wx[3] + bs0[3];
      const float ig = sigm(pi), fg = sigm(pf), gv = tanh_f(pg), og = sigm(po);
      c0  = fg * c0 + ig * gv;
      h0f = og * tanh_f(c0);

      const int p0 = (int)(unsigned)f2bf(h0f);
      const int e0 = __shfl(p0, lb), e1 = __shfl(p0, lb + 1),
                e2 = __shfl(p0, lb + 2), e3 = __shfl(p0, lb + 3);
      unsigned long long v0 = (unsigned long long)(unsigned short)e0 |
                              ((unsigned long long)(unsigned short)e1 << 16) |
                              ((unsigned long long)(unsigned short)e2 << 32) |
                              ((unsigned long long)(unsigned short)e3 << 48);
      v0 = (v0 & ~TB) | emn;
      if ((jlE & 3) == 0)        // plain store: write-through L1 -> stays dirty in local L2
        __hip_atomic_store(fb + i0, v0, __ATOMIC_RELAXED, __HIP_MEMORY_SCOPE_WORKGROUP);
      if (!uniform && (jlE & 3) == 1)   // cross-XCD safety net only when needed
        __hip_atomic_store(sb + i0, v0, __ATOMIC_RELAXED, __HIP_MEMORY_SCOPE_AGENT);
    }

    if (s >= 1u) {
      const float pi = GL[((1 * 4 + 0) * 16 + rowE) * 33 + jlE] + bs1[0];
      const float pf = GL[((1 * 4 + 1) * 16 + rowE) * 33 + jlE] + bs1[1];
      const float pg = GL[((1 * 4 + 2) * 16 + rowE) * 33 + jlE] + bs1[2];
      const float po = GL[((1 * 4 + 3) * 16 + rowE) * 33 + jlE] + bs1[3];
      const float ig = sigm(pi), fg = sigm(pf), gv = tanh_f(pg), og = sigm(po);
      c1  = fg * c1 + ig * gv;
      h1f = og * tanh_f(c1);
    }

    if (s < TSTEPS) {
      const int p1 = (int)(unsigned)f2bf(h1f);
      const int e0 = __shfl(p1, lb), e1 = __shfl(p1, lb + 1),
                e2 = __shfl(p1, lb + 2), e3 = __shfl(p1, lb + 3);
      unsigned long long v1 = (unsigned long long)(unsigned short)e0 |
                              ((unsigned long long)(unsigned short)e1 << 16) |
                              ((unsigned long long)(unsigned short)e2 << 32) |
                              ((unsigned long long)(unsigned short)e3 << 48);
      v1 = (v1 & ~TB) | emn;
      if ((jlE & 3) == 0)
        __hip_atomic_store(fb + i1, v1, __ATOMIC_RELAXED, __HIP_MEMORY_SCOPE_WORKGROUP);
      if (!uniform && (jlE & 3) == 1)
        __hip_atomic_store(sb + i1, v1, __ATOMIC_RELAXED, __HIP_MEMORY_SCOPE_AGENT);
    }
  }

  // ---- epilogue
  {
    const int b  = (c << 4) + rowE;
    const int jg = (iw << 5) + jlE;
    const size_t o = (size_t)b * 256 + jg;
    out[o]                  = h0f;
    out[65536 + o]          = h1f;
    out[131072 + o]         = c0;
    out[131072 + 65536 + o] = c1;
  }
}

extern "C" void kernel_launch(void* const* d_in, const int* in_sizes, int n_in,
                              void* d_out, int out_size, void* d_ws, size_t ws_size,
                              hipStream_t stream) {
  const float* x    = (const float*)d_in[0];
  const float* Wih0 = (const float*)d_in[1];
  const float* Whh0 = (const float*)d_in[2];
  const float* bih0 = (const float*)d_in[3];
  const float* bhh0 = (const float*)d_in[4];
  const float* Wih1 = (const float*)d_in[5];
  const float* Whh1 = (const float*)d_in[6];
  const float* bih1 = (const float*)d_in[7];
  const float* bhh1 = (const float*)d_in[8];

  unsigned long long* fastb = (unsigned long long*)d_ws;
  unsigned long long* slowb;
  unsigned* ctrl;
  if (ws_size >= (1u << 20) + 1024u) {
    slowb = fastb + 65536;                         // @512KB
    ctrl  = (unsigned*)(fastb + 131072);           // @1MB (144 u32 used)
  } else {
    slowb = fastb;                                 // alias (degraded; benign when uniform)
    ctrl  = (unsigned*)((char*)d_ws + (512u << 10));
  }

  lstm2_v4<<<128, 512, 0, stream>>>(x, Wih0, Whh0, bih0, bhh0,
                                    Wih1, Whh1, bih1, bhh1,
                                    (float*)d_out, fastb, slowb, ctrl);
}

// Round 5
// 2077.284 us; speedup vs baseline: 1.4185x; 1.1305x over previous
//
#include <hip/hip_runtime.h>

// 2-layer LSTM (B=256, T=1024, H=256, IN=1) inference; out = h_n[2,256,256], c_n[2,256,256] f32.
//
// v5: 16 clusters (16 batch rows) x 16 WGs x 256 thr (4 waves). Each wave owns 16 gate-cols
// (4 j x 4 gates, permuted m = jl*4 + gate) of Whh0/Wih1/Whh1 as register-resident MFMA
// *A*-operand fragments; h is the B-operand (swapped-operand trick). D layout then puts the
// 4 gates of one (row, j) element into acc[0..3] of a single lane -> cell update is fully
// lane-local: NO gate-tile LDS round trip, no second LDS structure at all.
// Split-poll skew: critical chain is poll h0 -> BAR1 -> 8 MFMA -> elementwise -> publish h0;
// layer 1 (16 MFMA, A0 kept in regs) + its poll run after, off the critical path.
// Exchange: tagged self-validating u64 chunks (bit14 of each bf16 is 0 since |h|<1), parity
// double-buffered; workgroup-scope stores (stay dirty in same-XCD L2) when the runtime XCD
// handshake confirms uniform placement, agent-scope mirror fallback otherwise. 0xAA poison
// reads as tag 0, never live at first use -> no ws init needed.

#define TSTEPS 1024u

typedef __attribute__((ext_vector_type(8))) short bf16x8;
typedef __attribute__((ext_vector_type(4))) float f32x4;

__device__ __forceinline__ unsigned short f2bf(float f) {
  unsigned u = __float_as_uint(f);
  u += 0x7FFFu + ((u >> 16) & 1u);   // RNE
  return (unsigned short)(u >> 16);
}
__device__ __forceinline__ float sigm(float x) { return 1.0f / (1.0f + __expf(-x)); }
__device__ __forceinline__ float tanh_f(float x) {
  float xc = fminf(fmaxf(x, -15.0f), 15.0f);
  float e = __expf(2.0f * xc);
  return (e - 1.0f) / (e + 1.0f);
}

__global__ __launch_bounds__(256, 1) void lstm2_v5(
    const float* __restrict__ x,     // [256][1024]
    const float* __restrict__ Wih0,  // [1024][1]
    const float* __restrict__ Whh0,  // [1024][256]
    const float* __restrict__ bih0, const float* __restrict__ bhh0,
    const float* __restrict__ Wih1,  // [1024][256]
    const float* __restrict__ Whh1,  // [1024][256]
    const float* __restrict__ bih1, const float* __restrict__ bhh1,
    float* __restrict__ out,                      // [4][256][256]
    unsigned long long* __restrict__ fastb,       // [2][16c][2L][16row][64q] u64 = 512KB
    unsigned long long* __restrict__ slowb,       // mirror (agent-coherent fallback)
    unsigned* __restrict__ ctrl)                  // [256] xcc slots + [16] decisions
{
  const int bid  = blockIdx.x;   // 256 WGs; cluster c = bid&15 -> WGs {c, c+16, ...}: one XCD
  const int c    = bid & 15;
  const int iw   = bid >> 4;     // 0..15: j-block of 16 hidden cols
  const int tid  = threadIdx.x;
  const int lane = tid & 63;
  const int wv   = tid >> 6;     // wave 0..3
  const int hi   = lane >> 4;    // 0..3
  const int lm   = lane & 15;

  const unsigned long long TB = 0x4000400040004000ULL;  // tag slots (bit14 of each bf16)

  // ---- publish my XCD id (agent scope)
  unsigned myxcc;
  asm volatile("s_getreg_b32 %0, hwreg(HW_REG_XCC_ID)" : "=s"(myxcc));
  myxcc &= 0xFu;
  if (tid == 0)
    __hip_atomic_store(&ctrl[bid], 0x5A5A0000u | myxcc,
                       __ATOMIC_RELAXED, __HIP_MEMORY_SCOPE_AGENT);

  // ---- weight A-operand fragments. Tile col m = jl*4 + gate  (gate = m&3, jl = m>>2)
  //      lane holds A row m=lm, k-chunk (hi*8 + kk*32). Global W row = gate*256 + jglobal.
  bf16x8 w0[8], wi1[8], wh1[8];
  {
    const int wrow = (lm & 3) * 256 + (iw << 4) + (wv << 2) + (lm >> 2);
    const int kb   = hi << 3;
#pragma unroll
    for (int kk = 0; kk < 8; ++kk) {
      const int k0 = kk * 32 + kb;
      const float* p0 = Whh0 + (size_t)wrow * 256 + k0;
      const float* p1 = Wih1 + (size_t)wrow * 256 + k0;
      const float* p2 = Whh1 + (size_t)wrow * 256 + k0;
      bf16x8 a, b, cc;
#pragma unroll
      for (int e = 0; e < 8; ++e) {
        a[e]  = (short)f2bf(p0[e]);
        b[e]  = (short)f2bf(p1[e]);
        cc[e] = (short)f2bf(p2[e]);
      }
      w0[kk] = a; wi1[kk] = b; wh1[kk] = cc;
    }
  }

  // ---- elementwise constants (lane-local element: batch row = lm, j = jg)
  const int rowE = lm;
  const int jg   = (iw << 4) + (wv << 2) + hi;
  float wx[4], bs0[4], bs1[4];
#pragma unroll
  for (int r = 0; r < 4; ++r) {
    const int col = (r << 8) + jg;
    wx[r]  = Wih0[col];
    bs0[r] = bih0[col] + bhh0[col];
    bs1[r] = bih1[col] + bhh1[col];
  }

  // ---- poll slots: 4 chunks/thread per layer; q = tid&63 fixed, rows vary
  unsigned ofs0[4], lofs0[4];
#pragma unroll
  for (int i = 0; i < 4; ++i) {
    const int n   = tid + 256 * i;
    const int row = (n >> 6) & 15;
    const int q   = n & 63;
    ofs0[i]  = (unsigned)(((c * 2 + 0) * 16 + row) * 64 + q);
    lofs0[i] = (unsigned)(row * 264 + q * 4);
  }
  // h1 chunks: ofs0[i] + 1024 ; LDS: lofs0[i] + 4224

  // ---- XCD uniformity handshake (WG iw==0 of each cluster decides)
  __shared__ unsigned s_uni;
  if (tid == 0) {
    if (iw == 0) {
      unsigned x0 = 0, uni = 1u;
      for (int k = 0; k < 16 && uni; ++k) {
        unsigned v; int g2 = 0;
        for (;;) {
          v = __hip_atomic_load(&ctrl[c + 16 * k], __ATOMIC_RELAXED, __HIP_MEMORY_SCOPE_AGENT);
          if ((v & 0xFFFF0000u) == 0x5A5A0000u) break;
          if (++g2 > (1 << 15)) { uni = 0u; break; }
        }
        if (uni) {
          const unsigned xc = v & 0xFFFFu;
          if (k == 0) x0 = xc; else if (xc != x0) uni = 0u;
        }
      }
      __hip_atomic_store(&ctrl[256 + c], 0x5A5A0000u | uni,
                         __ATOMIC_RELAXED, __HIP_MEMORY_SCOPE_AGENT);
    }
    unsigned uni = 0u; int g2 = 0;
    for (;;) {
      unsigned v = __hip_atomic_load(&ctrl[256 + c], __ATOMIC_RELAXED, __HIP_MEMORY_SCOPE_AGENT);
      if ((v & 0xFFFF0000u) == 0x5A5A0000u) { uni = v & 1u; break; }
      if (++g2 > (1 << 15)) break;
    }
    s_uni = uni;
  }
  __syncthreads();
  const bool uniform = (s_uni != 0u);
  unsigned long long* pollb = uniform ? fastb : slowb;

  __shared__ __align__(16) unsigned short A[2 * 16 * 264];  // [L][row][k], pad 264

  const float* xrow = x + (size_t)((c << 4) + rowE) * TSTEPS;

  float c0 = 0.f, h0f = 0.f, c1 = 0.f, h1f = 0.f;
  bool dead = false;

  for (unsigned s = 0; s <= TSTEPS; ++s) {
    const float xv = (s < TSTEPS) ? xrow[s] : 0.f;

    const unsigned t4 = s & 15u;
    const unsigned long long em =
        ((unsigned long long)(t4 & 1u)        << 14) |
        ((unsigned long long)((t4 >> 1) & 1u) << 30) |
        ((unsigned long long)((t4 >> 2) & 1u) << 46) |
        ((unsigned long long)((t4 >> 3) & 1u) << 62);
    const unsigned tau = s + 1u;
    const unsigned long long emn =
        ((unsigned long long)(tau & 1u)        << 14) |
        ((unsigned long long)((tau >> 1) & 1u) << 30) |
        ((unsigned long long)((tau >> 2) & 1u) << 46) |
        ((unsigned long long)((tau >> 3) & 1u) << 62);
    unsigned long long* fb = fastb + (size_t)(tau & 1u) * 32768u;
    unsigned long long* sb = slowb + (size_t)(tau & 1u) * 32768u;
    const unsigned long long* pb = pollb + (size_t)(s & 1u) * 32768u;

    // ---- phase 1: poll + stage A0 = h0[s-1]
    if (s == 0) {
      for (int z = tid; z < 2112; z += 256) ((unsigned*)A)[z] = 0u;  // zero both A0,A1
    } else {
      unsigned long long vv[4] = {0, 0, 0, 0};
      int guard = 0;
      while (!dead) {
#pragma unroll
        for (int i = 0; i < 4; ++i)
          vv[i] = __hip_atomic_load(pb + ofs0[i], __ATOMIC_RELAXED, __HIP_MEMORY_SCOPE_AGENT);
        const bool ok = ((vv[0] & TB) == em) & ((vv[1] & TB) == em) &
                        ((vv[2] & TB) == em) & ((vv[3] & TB) == em);
        if (__all(ok)) break;
        if (++guard > (1 << 14)) dead = true;
      }
#pragma unroll
      for (int i = 0; i < 4; ++i)
        *(unsigned long long*)&A[lofs0[i]] = vv[i] & ~TB;
    }
    __syncthreads();   // BAR1: A0 ready

    // ---- phase 2: layer0 MFMA (weights = A-operand), keep h0 frags for layer1
    bf16x8 af0[8];
    f32x4 acc0 = {0.f, 0.f, 0.f, 0.f};
    {
      const unsigned short* a0p = &A[lm * 264 + (hi << 3)];
#pragma unroll
      for (int kk = 0; kk < 8; ++kk) {
        af0[kk] = *(const bf16x8*)(a0p + kk * 32);
        acc0 = __builtin_amdgcn_mfma_f32_16x16x32_bf16(w0[kk], af0[kk], acc0, 0, 0, 0);
      }
    }

    // ---- phase 3: layer0 cell update (lane-local: acc0[r] = gate r) + publish h0
    if (s < TSTEPS) {
      const float pi = acc0[0] + xv * wx[0] + bs0[0];
      const float pf = acc0[1] + xv * wx[1] + bs0[1];
      const float pg = acc0[2] + xv * wx[2] + bs0[2];
      const float po = acc0[3] + xv * wx[3] + bs0[3];
      const float ig = sigm(pi), fg = sigm(pf), gv = tanh_f(pg), og = sigm(po);
      c0  = fg * c0 + ig * gv;
      h0f = og * tanh_f(c0);

      // pack 4 j (hi 0..3) of one row into u64: xor16 then xor32, lanes hi==0 store
      const int v  = (int)(unsigned)f2bf(h0f);
      const int p16 = __shfl_xor(v, 16);
      const unsigned part = (unsigned)(unsigned short)v | ((unsigned)(unsigned short)p16 << 16);
      const unsigned p32  = (unsigned)__shfl_xor((int)part, 32);
      unsigned long long v64 = (unsigned long long)part | ((unsigned long long)p32 << 32);
      v64 = (v64 & ~TB) | emn;
      const unsigned i0 = ((c * 2 + 0) * 16 + (unsigned)rowE) * 64 + (unsigned)((iw << 2) + wv);
      if (hi == 0) {
        __hip_atomic_store(fb + i0, v64, __ATOMIC_RELAXED, __HIP_MEMORY_SCOPE_WORKGROUP);
        if (!uniform)
          __hip_atomic_store(sb + i0, v64, __ATOMIC_RELAXED, __HIP_MEMORY_SCOPE_AGENT);
      }
    }

    // ---- phase 4: poll + stage A1 = h1[s-2] (off the h0 critical path)
    if (s >= 1u) {
      unsigned long long vv[4] = {0, 0, 0, 0};
      int guard = 0;
      while (!dead) {
#pragma unroll
        for (int i = 0; i < 4; ++i)
          vv[i] = __hip_atomic_load(pb + (ofs0[i] + 1024u),
                                    __ATOMIC_RELAXED, __HIP_MEMORY_SCOPE_AGENT);
        const bool ok = ((vv[0] & TB) == em) & ((vv[1] & TB) == em) &
                        ((vv[2] & TB) == em) & ((vv[3] & TB) == em);
        if (__all(ok)) break;
        if (++guard > (1 << 14)) dead = true;
      }
#pragma unroll
      for (int i = 0; i < 4; ++i)
        *(unsigned long long*)&A[lofs0[i] + 4224u] = vv[i] & ~TB;
    }
    __syncthreads();   // BAR2: A1 ready

    // ---- phase 5: layer1 MFMA: acc1 = Wih1*h0[s-1] (regs) + Whh1*h1[s-2] (LDS)
    f32x4 acc1a = {0.f, 0.f, 0.f, 0.f};
    f32x4 acc1b = {0.f, 0.f, 0.f, 0.f};
    {
      const unsigned short* a1p = &A[4224 + lm * 264 + (hi << 3)];
#pragma unroll
      for (int kk = 0; kk < 8; ++kk) {
        acc1a = __builtin_amdgcn_mfma_f32_16x16x32_bf16(wi1[kk], af0[kk], acc1a, 0, 0, 0);
        const bf16x8 a1f = *(const bf16x8*)(a1p + kk * 32);
        acc1b = __builtin_amdgcn_mfma_f32_16x16x32_bf16(wh1[kk], a1f, acc1b, 0, 0, 0);
      }
    }

    // ---- phase 6: layer1 cell update + publish h1
    if (s >= 1u) {
      const float pi = acc1a[0] + acc1b[0] + bs1[0];
      const float pf = acc1a[1] + acc1b[1] + bs1[1];
      const float pg = acc1a[2] + acc1b[2] + bs1[2];
      const float po = acc1a[3] + acc1b[3] + bs1[3];
      const float ig = sigm(pi), fg = sigm(pf), gv = tanh_f(pg), og = sigm(po);
      c1  = fg * c1 + ig * gv;
      h1f = og * tanh_f(c1);
    }
    if (s < TSTEPS) {
      const int v  = (int)(unsigned)f2bf(h1f);
      const int p16 = __shfl_xor(v, 16);
      const unsigned part = (unsigned)(unsigned short)v | ((unsigned)(unsigned short)p16 << 16);
      const unsigned p32  = (unsigned)__shfl_xor((int)part, 32);
      unsigned long long v64 = (unsigned long long)part | ((unsigned long long)p32 << 32);
      v64 = (v64 & ~TB) | emn;
      const unsigned i1 = ((c * 2 + 1) * 16 + (unsigned)rowE) * 64 + (unsigned)((iw << 2) + wv);
      if (hi == 0) {
        __hip_atomic_store(fb + i1, v64, __ATOMIC_RELAXED, __HIP_MEMORY_SCOPE_WORKGROUP);
        if (!uniform)
          __hip_atomic_store(sb + i1, v64, __ATOMIC_RELAXED, __HIP_MEMORY_SCOPE_AGENT);
      }
    }
  }

  // ---- epilogue: lane-local finals
  {
    const int b  = (c << 4) + rowE;
    const size_t o = (size_t)b * 256 + jg;
    out[o]                  = h0f;   // h_n layer 0
    out[65536 + o]          = h1f;   // h_n layer 1
    out[131072 + o]         = c0;    // c_n layer 0
    out[131072 + 65536 + o] = c1;    // c_n layer 1
  }
}

extern "C" void kernel_launch(void* const* d_in, const int* in_sizes, int n_in,
                              void* d_out, int out_size, void* d_ws, size_t ws_size,
                              hipStream_t stream) {
  const float* x    = (const float*)d_in[0];
  const float* Wih0 = (const float*)d_in[1];
  const float* Whh0 = (const float*)d_in[2];
  const float* bih0 = (const float*)d_in[3];
  const float* bhh0 = (const float*)d_in[4];
  const float* Wih1 = (const float*)d_in[5];
  const float* Whh1 = (const float*)d_in[6];
  const float* bih1 = (const float*)d_in[7];
  const float* bhh1 = (const float*)d_in[8];

  unsigned long long* fastb = (unsigned long long*)d_ws;
  unsigned long long* slowb;
  unsigned* ctrl;
  if (ws_size >= (1u << 20) + 2048u) {
    slowb = fastb + 65536;                      // @512KB
    ctrl  = (unsigned*)(fastb + 131072);        // @1MB (272 u32 used)
  } else {
    slowb = fastb;                              // alias (benign when uniform)
    ctrl  = (unsigned*)((char*)d_ws + (512u << 10));
  }

  lstm2_v5<<<256, 256, 0, stream>>>(x, Wih0, Whh0, bih0, bhh0,
                                    Wih1, Whh1, bih1, bhh1,
                                    (float*)d_out, fastb, slowb, ctrl);
}

// Round 6
// 1812.497 us; speedup vs baseline: 1.6257x; 1.1461x over previous
//
#include <hip/hip_runtime.h>

// 2-layer LSTM (B=256, T=1024, H=256, IN=1) inference; out = h_n[2,256,256], c_n[2,256,256] f32.
//
// v6: 16 clusters x 16 WGs x 256 thr (4 waves). Weights = register-resident MFMA *A*-operand
// (swapped-operand trick, tile col m = jl*4+gate) so the cell update is fully lane-local.
// ONE exchange rendezvous per step: poll h0[s-1] AND h1[s-2] together (h1 has a full step of
// slack -> never waits), stage into parity-double-buffered LDS A, ONE barrier, then
// mfma0 -> mfma1 (matrix pipe) overlapping elem0 (VALU), publish h0 early, elem1, publish h1.
// Accumulator chains split 2x/4x for latency. Exchange: tagged self-validating u64 chunks
// (bit14 of each bf16 is 0 since |h|<1), parity slots; workgroup-scope stores stay dirty in the
// same-XCD L2 (runtime XCC_ID handshake; agent-scope mirror fallback if placement non-uniform).
// 0xAA poison reads as tag 0 -> never a live tag at first use -> no ws init needed.

#define TSTEPS 1024u

typedef __attribute__((ext_vector_type(8))) short bf16x8;
typedef __attribute__((ext_vector_type(4))) float f32x4;

__device__ __forceinline__ unsigned short f2bf(float f) {
  unsigned u = __float_as_uint(f);
  u += 0x7FFFu + ((u >> 16) & 1u);   // RNE
  return (unsigned short)(u >> 16);
}
__device__ __forceinline__ float sigm(float x) { return 1.0f / (1.0f + __expf(-x)); }
__device__ __forceinline__ float tanh_f(float x) {
  float xc = fminf(fmaxf(x, -15.0f), 15.0f);
  float e = __expf(2.0f * xc);
  return (e - 1.0f) / (e + 1.0f);
}

__global__ __launch_bounds__(256, 1) void lstm2_v6(
    const float* __restrict__ x,     // [256][1024]
    const float* __restrict__ Wih0,  // [1024][1]
    const float* __restrict__ Whh0,  // [1024][256]
    const float* __restrict__ bih0, const float* __restrict__ bhh0,
    const float* __restrict__ Wih1,  // [1024][256]
    const float* __restrict__ Whh1,  // [1024][256]
    const float* __restrict__ bih1, const float* __restrict__ bhh1,
    float* __restrict__ out,                      // [4][256][256]
    unsigned long long* __restrict__ fastb,       // [2][16c][2L][16row][64q] u64 = 512KB
    unsigned long long* __restrict__ slowb,       // mirror (agent-coherent fallback)
    unsigned* __restrict__ ctrl)                  // [256] xcc slots + [16] decisions
{
  const int bid  = blockIdx.x;   // 256 WGs; cluster c = bid&15 -> WGs {c, c+16, ...}: one XCD
  const int c    = bid & 15;
  const int iw   = bid >> 4;     // 0..15: j-block of 16 hidden cols
  const int tid  = threadIdx.x;
  const int lane = tid & 63;
  const int wv   = tid >> 6;     // wave 0..3
  const int hi   = lane >> 4;    // 0..3
  const int lm   = lane & 15;

  const unsigned long long TB = 0x4000400040004000ULL;  // tag slots (bit14 of each bf16)

  // ---- publish my XCD id (agent scope)
  unsigned myxcc;
  asm volatile("s_getreg_b32 %0, hwreg(HW_REG_XCC_ID)" : "=s"(myxcc));
  myxcc &= 0xFu;
  if (tid == 0)
    __hip_atomic_store(&ctrl[bid], 0x5A5A0000u | myxcc,
                       __ATOMIC_RELAXED, __HIP_MEMORY_SCOPE_AGENT);

  // ---- weight A-operand fragments. Tile col m = jl*4 + gate (gate = m&3, jl = m>>2).
  bf16x8 w0[8], wi1[8], wh1[8];
  {
    const int wrow = (lm & 3) * 256 + (iw << 4) + (wv << 2) + (lm >> 2);
    const int kb   = hi << 3;
#pragma unroll
    for (int kk = 0; kk < 8; ++kk) {
      const int k0 = kk * 32 + kb;
      const float* p0 = Whh0 + (size_t)wrow * 256 + k0;
      const float* p1 = Wih1 + (size_t)wrow * 256 + k0;
      const float* p2 = Whh1 + (size_t)wrow * 256 + k0;
      bf16x8 a, b, cc;
#pragma unroll
      for (int e = 0; e < 8; ++e) {
        a[e]  = (short)f2bf(p0[e]);
        b[e]  = (short)f2bf(p1[e]);
        cc[e] = (short)f2bf(p2[e]);
      }
      w0[kk] = a; wi1[kk] = b; wh1[kk] = cc;
    }
  }

  // ---- elementwise constants (lane-local element: batch row = lm, j = jg)
  const int rowE = lm;
  const int jg   = (iw << 4) + (wv << 2) + hi;
  float wx[4], bs0[4], bs1[4];
#pragma unroll
  for (int r = 0; r < 4; ++r) {
    const int col = (r << 8) + jg;
    wx[r]  = Wih0[col];
    bs0[r] = bih0[col] + bhh0[col];
    bs1[r] = bih1[col] + bhh1[col];
  }

  // ---- merged poll slots: 8 chunks/thread covering both layers (2048 chunks total)
  unsigned ofs_[8], lofs_[8];
#pragma unroll
  for (int i = 0; i < 8; ++i) {
    const int n   = tid + 256 * i;
    const int L   = n >> 10;
    const int row = (n >> 6) & 15;
    const int q   = n & 63;
    ofs_[i]  = (unsigned)(((c * 2 + L) * 16 + row) * 64 + q);
    lofs_[i] = (unsigned)(L * 4224 + row * 264 + q * 4);   // within one parity region
  }

  // ---- XCD uniformity handshake (WG iw==0 of each cluster decides)
  __shared__ unsigned s_uni;
  if (tid == 0) {
    if (iw == 0) {
      unsigned x0 = 0, uni = 1u;
      for (int k = 0; k < 16 && uni; ++k) {
        unsigned v; int g2 = 0;
        for (;;) {
          v = __hip_atomic_load(&ctrl[c + 16 * k], __ATOMIC_RELAXED, __HIP_MEMORY_SCOPE_AGENT);
          if ((v & 0xFFFF0000u) == 0x5A5A0000u) break;
          if (++g2 > (1 << 15)) { uni = 0u; break; }
        }
        if (uni) {
          const unsigned xc = v & 0xFFFFu;
          if (k == 0) x0 = xc; else if (xc != x0) uni = 0u;
        }
      }
      __hip_atomic_store(&ctrl[256 + c], 0x5A5A0000u | uni,
                         __ATOMIC_RELAXED, __HIP_MEMORY_SCOPE_AGENT);
    }
    unsigned uni = 0u; int g2 = 0;
    for (;;) {
      unsigned v = __hip_atomic_load(&ctrl[256 + c], __ATOMIC_RELAXED, __HIP_MEMORY_SCOPE_AGENT);
      if ((v & 0xFFFF0000u) == 0x5A5A0000u) { uni = v & 1u; break; }
      if (++g2 > (1 << 15)) break;
    }
    s_uni = uni;
  }
  __syncthreads();
  const bool uniform = (s_uni != 0u);
  unsigned long long* pollb = uniform ? fastb : slowb;

  __shared__ __align__(16) unsigned short A[2 * 2 * 16 * 264];  // [parity][L][row][264]

  const float* xrow = x + (size_t)((c << 4) + rowE) * TSTEPS;
  float4 xq = {0.f, 0.f, 0.f, 0.f};

  float c0 = 0.f, h0f = 0.f, c1 = 0.f, h1f = 0.f;
  bool dead = false;

  for (unsigned s = 0; s <= TSTEPS; ++s) {
    if ((s & 3u) == 0u && s < TSTEPS) xq = *(const float4*)(xrow + s);
    const float xv = (s & 2u) ? ((s & 1u) ? xq.w : xq.z) : ((s & 1u) ? xq.y : xq.x);

    const unsigned t4 = s & 15u;
    const unsigned long long em =
        ((unsigned long long)(t4 & 1u)        << 14) |
        ((unsigned long long)((t4 >> 1) & 1u) << 30) |
        ((unsigned long long)((t4 >> 2) & 1u) << 46) |
        ((unsigned long long)((t4 >> 3) & 1u) << 62);
    const unsigned tau = s + 1u;
    const unsigned long long emn =
        ((unsigned long long)(tau & 1u)        << 14) |
        ((unsigned long long)((tau >> 1) & 1u) << 30) |
        ((unsigned long long)((tau >> 2) & 1u) << 46) |
        ((unsigned long long)((tau >> 3) & 1u) << 62);
    unsigned long long* fb = fastb + (size_t)(tau & 1u) * 32768u;
    unsigned long long* sb = slowb + (size_t)(tau & 1u) * 32768u;
    const unsigned long long* pb = pollb + (size_t)(s & 1u) * 32768u;
    unsigned short* Ap = A + (s & 1u) * 8448u;

    // ---- phase 1: merged poll of h0[s-1] (L=0) and h1[s-2] (L=1), stage into parity LDS
    if (s == 0) {
      for (int z = tid; z < 8448; z += 256) ((unsigned*)A)[z] = 0u;   // zero both parities
    } else {
      unsigned long long vv[8];
      int guard = 0;
      while (!dead) {
#pragma unroll
        for (int i = 0; i < 8; ++i)
          vv[i] = __hip_atomic_load(pb + ofs_[i], __ATOMIC_RELAXED, __HIP_MEMORY_SCOPE_AGENT);
        bool ok = true;
#pragma unroll
        for (int i = 0; i < 8; ++i) ok &= ((vv[i] & TB) == em);
        if (__all(ok)) break;
        if (++guard > (1 << 14)) dead = true;   // sticky bailout: fail visibly, never hang
      }
#pragma unroll
      for (int i = 0; i < 8; ++i)
        *(unsigned long long*)&Ap[lofs_[i]] = vv[i] & ~TB;
    }
    __syncthreads();   // the ONE barrier per step (parity buffers make it sufficient)

    // ---- phase 2: layer0 MFMA (2 split chains), keep h0 frags in regs for layer1
    bf16x8 af0[8];
    f32x4 acc0a = {0.f, 0.f, 0.f, 0.f}, acc0b = {0.f, 0.f, 0.f, 0.f};
    const unsigned short* a0p = Ap + lm * 264 + (hi << 3);
    const unsigned short* a1p = a0p + 4224;
#pragma unroll
    for (int kk = 0; kk < 4; ++kk) {
      af0[kk] = *(const bf16x8*)(a0p + kk * 32);
      acc0a = __builtin_amdgcn_mfma_f32_16x16x32_bf16(w0[kk], af0[kk], acc0a, 0, 0, 0);
    }
#pragma unroll
    for (int kk = 4; kk < 8; ++kk) {
      af0[kk] = *(const bf16x8*)(a0p + kk * 32);
      acc0b = __builtin_amdgcn_mfma_f32_16x16x32_bf16(w0[kk], af0[kk], acc0b, 0, 0, 0);
    }

    // ---- phase 3: layer1 MFMA issued now (matrix pipe overlaps elem0 VALU below)
    f32x4 a1a0 = {0.f, 0.f, 0.f, 0.f}, a1a1 = {0.f, 0.f, 0.f, 0.f};
    f32x4 a1b0 = {0.f, 0.f, 0.f, 0.f}, a1b1 = {0.f, 0.f, 0.f, 0.f};
#pragma unroll
    for (int kk = 0; kk < 4; ++kk) {
      a1a0 = __builtin_amdgcn_mfma_f32_16x16x32_bf16(wi1[kk], af0[kk], a1a0, 0, 0, 0);
      const bf16x8 a1f = *(const bf16x8*)(a1p + kk * 32);
      a1b0 = __builtin_amdgcn_mfma_f32_16x16x32_bf16(wh1[kk], a1f, a1b0, 0, 0, 0);
    }
#pragma unroll
    for (int kk = 4; kk < 8; ++kk) {
      a1a1 = __builtin_amdgcn_mfma_f32_16x16x32_bf16(wi1[kk], af0[kk], a1a1, 0, 0, 0);
      const bf16x8 a1f = *(const bf16x8*)(a1p + kk * 32);
      a1b1 = __builtin_amdgcn_mfma_f32_16x16x32_bf16(wh1[kk], a1f, a1b1, 0, 0, 0);
    }

    // ---- phase 4: layer0 cell update (lane-local) + EARLY h0 publish
    if (s < TSTEPS) {
      const float pi = (acc0a[0] + acc0b[0]) + xv * wx[0] + bs0[0];
      const float pf = (acc0a[1] + acc0b[1]) + xv * wx[1] + bs0[1];
      const float pg = (acc0a[2] + acc0b[2]) + xv * wx[2] + bs0[2];
      const float po = (acc0a[3] + acc0b[3]) + xv * wx[3] + bs0[3];
      const float ig = sigm(pi), fg = sigm(pf), gv = tanh_f(pg), og = sigm(po);
      c0  = fg * c0 + ig * gv;
      h0f = og * tanh_f(c0);

      const int v   = (int)(unsigned)f2bf(h0f);
      const int p16 = __shfl_xor(v, 16);
      const unsigned part = (unsigned)(unsigned short)v | ((unsigned)(unsigned short)p16 << 16);
      const unsigned p32  = (unsigned)__shfl_xor((int)part, 32);
      unsigned long long v64 = (unsigned long long)part | ((unsigned long long)p32 << 32);
      v64 = (v64 & ~TB) | emn;
      const unsigned i0 = ((c * 2 + 0) * 16 + (unsigned)rowE) * 64 + (unsigned)((iw << 2) + wv);
      if (hi == 0) {
        __hip_atomic_store(fb + i0, v64, __ATOMIC_RELAXED, __HIP_MEMORY_SCOPE_WORKGROUP);
        if (!uniform)
          __hip_atomic_store(sb + i0, v64, __ATOMIC_RELAXED, __HIP_MEMORY_SCOPE_AGENT);
      }
    }

    // ---- phase 5: layer1 cell update + h1 publish
    if (s >= 1u) {
      const float pi = (a1a0[0] + a1a1[0]) + (a1b0[0] + a1b1[0]) + bs1[0];
      const float pf = (a1a0[1] + a1a1[1]) + (a1b0[1] + a1b1[1]) + bs1[1];
      const float pg = (a1a0[2] + a1a1[2]) + (a1b0[2] + a1b1[2]) + bs1[2];
      const float po = (a1a0[3] + a1a1[3]) + (a1b0[3] + a1b1[3]) + bs1[3];
      const float ig = sigm(pi), fg = sigm(pf), gv = tanh_f(pg), og = sigm(po);
      c1  = fg * c1 + ig * gv;
      h1f = og * tanh_f(c1);
    }
    if (s < TSTEPS) {
      const int v   = (int)(unsigned)f2bf(h1f);
      const int p16 = __shfl_xor(v, 16);
      const unsigned part = (unsigned)(unsigned short)v | ((unsigned)(unsigned short)p16 << 16);
      const unsigned p32  = (unsigned)__shfl_xor((int)part, 32);
      unsigned long long v64 = (unsigned long long)part | ((unsigned long long)p32 << 32);
      v64 = (v64 & ~TB) | emn;
      const unsigned i1 = ((c * 2 + 1) * 16 + (unsigned)rowE) * 64 + (unsigned)((iw << 2) + wv);
      if (hi == 0) {
        __hip_atomic_store(fb + i1, v64, __ATOMIC_RELAXED, __HIP_MEMORY_SCOPE_WORKGROUP);
        if (!uniform)
          __hip_atomic_store(sb + i1, v64, __ATOMIC_RELAXED, __HIP_MEMORY_SCOPE_AGENT);
      }
    }
  }

  // ---- epilogue: lane-local finals
  {
    const int b  = (c << 4) + rowE;
    const size_t o = (size_t)b * 256 + jg;
    out[o]                  = h0f;   // h_n layer 0
    out[65536 + o]          = h1f;   // h_n layer 1
    out[131072 + o]         = c0;    // c_n layer 0
    out[131072 + 65536 + o] = c1;    // c_n layer 1
  }
}

extern "C" void kernel_launch(void* const* d_in, const int* in_sizes, int n_in,
                              void* d_out, int out_size, void* d_ws, size_t ws_size,
                              hipStream_t stream) {
  const float* x    = (const float*)d_in[0];
  const float* Wih0 = (const float*)d_in[1];
  const float* Whh0 = (const float*)d_in[2];
  const float* bih0 = (const float*)d_in[3];
  const float* bhh0 = (const float*)d_in[4];
  const float* Wih1 = (const float*)d_in[5];
  const float* Whh1 = (const float*)d_in[6];
  const float* bih1 = (const float*)d_in[7];
  const float* bhh1 = (const float*)d_in[8];

  unsigned long long* fastb = (unsigned long long*)d_ws;
  unsigned long long* slowb;
  unsigned* ctrl;
  if (ws_size >= (1u << 20) + 2048u) {
    slowb = fastb + 65536;                      // @512KB
    ctrl  = (unsigned*)(fastb + 131072);        // @1MB (272 u32 used)
  } else {
    slowb = fastb;                              // alias (benign when uniform)
    ctrl  = (unsigned*)((char*)d_ws + (512u << 10));
  }

  lstm2_v6<<<256, 256, 0, stream>>>(x, Wih0, Whh0, bih0, bhh0,
                                    Wih1, Whh1, bih1, bhh1,
                                    (float*)d_out, fastb, slowb, ctrl);
}

// Round 7
// 1806.526 us; speedup vs baseline: 1.6311x; 1.0033x over previous
//
#include <hip/hip_runtime.h>

// 2-layer LSTM (B=256, T=1024, H=256, IN=1) inference; out = h_n[2,256,256], c_n[2,256,256] f32.
//
// v7: 16 clusters x 16 WGs x 256 thr (4 waves). Weights = register-resident MFMA *A*-operand
// (swapped-operand trick) -> cell update fully lane-local. ONE rendezvous + ONE barrier per step.
// NEW vs v6: release-FLAG exchange protocol. Producers store plain bf16-packed u64 data, drain
// with s_waitcnt vmcnt(0), then set one flag per (WG,wave) (64 flags/cluster). Consumers spin on
// the 64 flags only (1KB/iter vs 16KB/iter of v6's tag-validated data re-reads -> kills the L2
// poll congestion), then load the data exactly once. Windowed flag match (f-(MAGIC+s) < 2^16)
// tolerates producers 1 step ahead (monotonic) while 0xAA poison never matches -> no ws init.
// Same overwrite-safety induction: slot-X writes at step s+1 are gated on all flags >= s+1,
// which requires every consumer to have finished its step-s reads of slot X.
// Placement: workgroup-scope stores stay dirty in the same-XCD L2 (runtime XCC_ID handshake);
// agent-scope mirror fallback if placement is non-uniform.

#define TSTEPS 1024u
#define FMAGIC 0x5A5A0000u

typedef __attribute__((ext_vector_type(8))) short bf16x8;
typedef __attribute__((ext_vector_type(4))) float f32x4;

__device__ __forceinline__ unsigned short f2bf(float f) {
  unsigned u = __float_as_uint(f);
  u += 0x7FFFu + ((u >> 16) & 1u);   // RNE
  return (unsigned short)(u >> 16);
}
__device__ __forceinline__ float sigm(float x) { return 1.0f / (1.0f + __expf(-x)); }
__device__ __forceinline__ float tanh_f(float x) {
  float xc = fminf(fmaxf(x, -15.0f), 15.0f);
  float e = __expf(2.0f * xc);
  return (e - 1.0f) / (e + 1.0f);
}

__global__ __launch_bounds__(256, 1) void lstm2_v7(
    const float* __restrict__ x,     // [256][1024]
    const float* __restrict__ Wih0,  // [1024][1]
    const float* __restrict__ Whh0,  // [1024][256]
    const float* __restrict__ bih0, const float* __restrict__ bhh0,
    const float* __restrict__ Wih1,  // [1024][256]
    const float* __restrict__ Whh1,  // [1024][256]
    const float* __restrict__ bih1, const float* __restrict__ bhh1,
    float* __restrict__ out,                      // [4][256][256]
    unsigned long long* __restrict__ fastb,       // [2][16c][2L][16row][64q] u64 = 512KB
    unsigned long long* __restrict__ slowb,       // mirror (agent-coherent fallback)
    unsigned* __restrict__ ctrl,                  // [256] xcc slots + [16] decisions
    unsigned* __restrict__ flagF,                 // [16c][64] release flags (L2-local)
    unsigned* __restrict__ flagS)                 // mirror flags (agent fallback)
{
  const int bid  = blockIdx.x;   // 256 WGs; cluster c = bid&15 -> WGs {c, c+16, ...}: one XCD
  const int c    = bid & 15;
  const int iw   = bid >> 4;     // 0..15: j-block of 16 hidden cols
  const int tid  = threadIdx.x;
  const int lane = tid & 63;
  const int wv   = tid >> 6;     // wave 0..3
  const int hi   = lane >> 4;    // 0..3
  const int lm   = lane & 15;

  // ---- publish my XCD id (agent scope)
  unsigned myxcc;
  asm volatile("s_getreg_b32 %0, hwreg(HW_REG_XCC_ID)" : "=s"(myxcc));
  myxcc &= 0xFu;
  if (tid == 0)
    __hip_atomic_store(&ctrl[bid], FMAGIC | myxcc,
                       __ATOMIC_RELAXED, __HIP_MEMORY_SCOPE_AGENT);

  // ---- weight A-operand fragments. Tile col m = jl*4 + gate (gate = m&3, jl = m>>2).
  bf16x8 w0[8], wi1[8], wh1[8];
  {
    const int wrow = (lm & 3) * 256 + (iw << 4) + (wv << 2) + (lm >> 2);
    const int kb   = hi << 3;
#pragma unroll
    for (int kk = 0; kk < 8; ++kk) {
      const int k0 = kk * 32 + kb;
      const float* p0 = Whh0 + (size_t)wrow * 256 + k0;
      const float* p1 = Wih1 + (size_t)wrow * 256 + k0;
      const float* p2 = Whh1 + (size_t)wrow * 256 + k0;
      bf16x8 a, b, cc;
#pragma unroll
      for (int e = 0; e < 8; ++e) {
        a[e]  = (short)f2bf(p0[e]);
        b[e]  = (short)f2bf(p1[e]);
        cc[e] = (short)f2bf(p2[e]);
      }
      w0[kk] = a; wi1[kk] = b; wh1[kk] = cc;
    }
  }

  // ---- elementwise constants (lane-local element: batch row = lm, j = jg)
  const int rowE = lm;
  const int jg   = (iw << 4) + (wv << 2) + hi;
  float wx[4], bs0[4], bs1[4];
#pragma unroll
  for (int r = 0; r < 4; ++r) {
    const int col = (r << 8) + jg;
    wx[r]  = Wih0[col];
    bs0[r] = bih0[col] + bhh0[col];
    bs1[r] = bih1[col] + bhh1[col];
  }

  // ---- data slots: 8 chunks/thread covering both layers (2048 chunks total)
  unsigned ofs_[8], lofs_[8];
#pragma unroll
  for (int i = 0; i < 8; ++i) {
    const int n   = tid + 256 * i;
    const int L   = n >> 10;
    const int row = (n >> 6) & 15;
    const int q   = n & 63;
    ofs_[i]  = (unsigned)(((c * 2 + L) * 16 + row) * 64 + q);
    lofs_[i] = (unsigned)(L * 4224 + row * 264 + q * 4);   // within one parity region
  }

  // ---- XCD uniformity handshake (WG iw==0 of each cluster decides)
  __shared__ unsigned s_uni;
  if (tid == 0) {
    if (iw == 0) {
      unsigned x0 = 0, uni = 1u;
      for (int k = 0; k < 16 && uni; ++k) {
        unsigned v; int g2 = 0;
        for (;;) {
          v = __hip_atomic_load(&ctrl[c + 16 * k], __ATOMIC_RELAXED, __HIP_MEMORY_SCOPE_AGENT);
          if ((v & 0xFFFF0000u) == FMAGIC) break;
          if (++g2 > (1 << 15)) { uni = 0u; break; }
        }
        if (uni) {
          const unsigned xc = v & 0xFFFFu;
          if (k == 0) x0 = xc; else if (xc != x0) uni = 0u;
        }
      }
      __hip_atomic_store(&ctrl[256 + c], FMAGIC | uni,
                         __ATOMIC_RELAXED, __HIP_MEMORY_SCOPE_AGENT);
    }
    unsigned uni = 0u; int g2 = 0;
    for (;;) {
      unsigned v = __hip_atomic_load(&ctrl[256 + c], __ATOMIC_RELAXED, __HIP_MEMORY_SCOPE_AGENT);
      if ((v & 0xFFFF0000u) == FMAGIC) { uni = v & 1u; break; }
      if (++g2 > (1 << 15)) break;
    }
    s_uni = uni;
  }
  __syncthreads();
  const bool uniform = (s_uni != 0u);
  unsigned long long* pollD = uniform ? fastb : slowb;
  unsigned*           pollF = uniform ? flagF : flagS;
  unsigned*           myFlagF = &flagF[(c << 6) + (iw << 2) + wv];
  unsigned*           myFlagS = &flagS[(c << 6) + (iw << 2) + wv];
  unsigned*           fl      = pollF + (c << 6);

  __shared__ __align__(16) unsigned short A[2 * 2 * 16 * 264];  // [parity][L][row][264]

  const float* xrow = x + (size_t)((c << 4) + rowE) * TSTEPS;
  float4 xq = {0.f, 0.f, 0.f, 0.f};

  float c0 = 0.f, h0f = 0.f, c1 = 0.f, h1f = 0.f;
  bool dead = false;

  for (unsigned s = 0; s <= TSTEPS; ++s) {
    if ((s & 3u) == 0u && s < TSTEPS) xq = *(const float4*)(xrow + s);
    const float xv = (s & 2u) ? ((s & 1u) ? xq.w : xq.z) : ((s & 1u) ? xq.y : xq.x);

    unsigned long long* fb = fastb + (size_t)((s + 1u) & 1u) * 32768u;
    unsigned long long* sb = slowb + (size_t)((s + 1u) & 1u) * 32768u;
    const unsigned long long* pb = pollD + (size_t)(s & 1u) * 32768u;
    unsigned short* Ap = A + (s & 1u) * 8448u;

    // ---- phase 1: flag rendezvous, then single data fetch + stage into parity LDS
    if (s == 0) {
      for (int z = tid; z < 8448; z += 256) ((unsigned*)A)[z] = 0u;   // zero both parities
    } else {
      const unsigned want = FMAGIC + s;   // accept flag in [want, want+65535] (skew<=1)
      int guard = 0;
      while (!dead) {
        const unsigned f = __hip_atomic_load(fl + lane, __ATOMIC_RELAXED, __HIP_MEMORY_SCOPE_AGENT);
        if (__all((int)((f - want) < 0x10000u))) break;
        if (++guard > (1 << 12)) dead = true;   // sticky bailout: fail visibly, never hang
      }
      unsigned long long vv[8];
#pragma unroll
      for (int i = 0; i < 8; ++i)
        vv[i] = __hip_atomic_load(pb + ofs_[i], __ATOMIC_RELAXED, __HIP_MEMORY_SCOPE_AGENT);
#pragma unroll
      for (int i = 0; i < 8; ++i)
        *(unsigned long long*)&Ap[lofs_[i]] = vv[i];
    }
    __syncthreads();   // the ONE barrier per step (parity buffers make it sufficient)

    // ---- phase 2: layer0 MFMA (2 split chains), keep h0 frags in regs for layer1
    bf16x8 af0[8];
    f32x4 acc0a = {0.f, 0.f, 0.f, 0.f}, acc0b = {0.f, 0.f, 0.f, 0.f};
    const unsigned short* a0p = Ap + lm * 264 + (hi << 3);
    const unsigned short* a1p = a0p + 4224;
#pragma unroll
    for (int kk = 0; kk < 4; ++kk) {
      af0[kk] = *(const bf16x8*)(a0p + kk * 32);
      acc0a = __builtin_amdgcn_mfma_f32_16x16x32_bf16(w0[kk], af0[kk], acc0a, 0, 0, 0);
    }
#pragma unroll
    for (int kk = 4; kk < 8; ++kk) {
      af0[kk] = *(const bf16x8*)(a0p + kk * 32);
      acc0b = __builtin_amdgcn_mfma_f32_16x16x32_bf16(w0[kk], af0[kk], acc0b, 0, 0, 0);
    }

    // ---- phase 3: layer1 MFMA issued now (matrix pipe overlaps elem0 VALU below)
    f32x4 a1a0 = {0.f, 0.f, 0.f, 0.f}, a1a1 = {0.f, 0.f, 0.f, 0.f};
    f32x4 a1b0 = {0.f, 0.f, 0.f, 0.f}, a1b1 = {0.f, 0.f, 0.f, 0.f};
#pragma unroll
    for (int kk = 0; kk < 4; ++kk) {
      a1a0 = __builtin_amdgcn_mfma_f32_16x16x32_bf16(wi1[kk], af0[kk], a1a0, 0, 0, 0);
      const bf16x8 a1f = *(const bf16x8*)(a1p + kk * 32);
      a1b0 = __builtin_amdgcn_mfma_f32_16x16x32_bf16(wh1[kk], a1f, a1b0, 0, 0, 0);
    }
#pragma unroll
    for (int kk = 4; kk < 8; ++kk) {
      a1a1 = __builtin_amdgcn_mfma_f32_16x16x32_bf16(wi1[kk], af0[kk], a1a1, 0, 0, 0);
      const bf16x8 a1f = *(const bf16x8*)(a1p + kk * 32);
      a1b1 = __builtin_amdgcn_mfma_f32_16x16x32_bf16(wh1[kk], a1f, a1b1, 0, 0, 0);
    }

    // ---- phase 4: layer0 cell update (lane-local) + EARLY h0 data store
    if (s < TSTEPS) {
      const float pi = (acc0a[0] + acc0b[0]) + xv * wx[0] + bs0[0];
      const float pf = (acc0a[1] + acc0b[1]) + xv * wx[1] + bs0[1];
      const float pg = (acc0a[2] + acc0b[2]) + xv * wx[2] + bs0[2];
      const float po = (acc0a[3] + acc0b[3]) + xv * wx[3] + bs0[3];
      const float ig = sigm(pi), fg = sigm(pf), gv = tanh_f(pg), og = sigm(po);
      c0  = fg * c0 + ig * gv;
      h0f = og * tanh_f(c0);

      const int v   = (int)(unsigned)f2bf(h0f);
      const int p16 = __shfl_xor(v, 16);
      const unsigned part = (unsigned)(unsigned short)v | ((unsigned)(unsigned short)p16 << 16);
      const unsigned p32  = (unsigned)__shfl_xor((int)part, 32);
      const unsigned long long v64 = (unsigned long long)part | ((unsigned long long)p32 << 32);
      const unsigned i0 = ((c * 2 + 0) * 16 + (unsigned)rowE) * 64 + (unsigned)((iw << 2) + wv);
      if (hi == 0) {
        __hip_atomic_store(fb + i0, v64, __ATOMIC_RELAXED, __HIP_MEMORY_SCOPE_WORKGROUP);
        if (!uniform)
          __hip_atomic_store(sb + i0, v64, __ATOMIC_RELAXED, __HIP_MEMORY_SCOPE_AGENT);
      }
    }

    // ---- phase 5: layer1 cell update + h1 data store
    if (s >= 1u) {
      const float pi = (a1a0[0] + a1a1[0]) + (a1b0[0] + a1b1[0]) + bs1[0];
      const float pf = (a1a0[1] + a1a1[1]) + (a1b0[1] + a1b1[1]) + bs1[1];
      const float pg = (a1a0[2] + a1a1[2]) + (a1b0[2] + a1b1[2]) + bs1[2];
      const float po = (a1a0[3] + a1a1[3]) + (a1b0[3] + a1b1[3]) + bs1[3];
      const float ig = sigm(pi), fg = sigm(pf), gv = tanh_f(pg), og = sigm(po);
      c1  = fg * c1 + ig * gv;
      h1f = og * tanh_f(c1);
    }
    if (s < TSTEPS) {
      const int v   = (int)(unsigned)f2bf(h1f);
      const int p16 = __shfl_xor(v, 16);
      const unsigned part = (unsigned)(unsigned short)v | ((unsigned)(unsigned short)p16 << 16);
      const unsigned p32  = (unsigned)__shfl_xor((int)part, 32);
      const unsigned long long v64 = (unsigned long long)part | ((unsigned long long)p32 << 32);
      const unsigned i1 = ((c * 2 + 1) * 16 + (unsigned)rowE) * 64 + (unsigned)((iw << 2) + wv);
      if (hi == 0) {
        __hip_atomic_store(fb + i1, v64, __ATOMIC_RELAXED, __HIP_MEMORY_SCOPE_WORKGROUP);
        if (!uniform)
          __hip_atomic_store(sb + i1, v64, __ATOMIC_RELAXED, __HIP_MEMORY_SCOPE_AGENT);
      }

      // ---- release: drain data stores to L2, then set this wave's flag
      asm volatile("s_waitcnt vmcnt(0)" ::: "memory");
      if (lane == 0) {
        const unsigned fv = FMAGIC + s + 1u;
        if (uniform)
          __hip_atomic_store(myFlagF, fv, __ATOMIC_RELAXED, __HIP_MEMORY_SCOPE_WORKGROUP);
        else
          __hip_atomic_store(myFlagS, fv, __ATOMIC_RELAXED, __HIP_MEMORY_SCOPE_AGENT);
      }
    }
  }

  // ---- epilogue: lane-local finals
  {
    const int b  = (c << 4) + rowE;
    const size_t o = (size_t)b * 256 + jg;
    out[o]                  = h0f;   // h_n layer 0
    out[65536 + o]          = h1f;   // h_n layer 1
    out[131072 + o]         = c0;    // c_n layer 0
    out[131072 + 65536 + o] = c1;    // c_n layer 1
  }
}

extern "C" void kernel_launch(void* const* d_in, const int* in_sizes, int n_in,
                              void* d_out, int out_size, void* d_ws, size_t ws_size,
                              hipStream_t stream) {
  const float* x    = (const float*)d_in[0];
  const float* Wih0 = (const float*)d_in[1];
  const float* Whh0 = (const float*)d_in[2];
  const float* bih0 = (const float*)d_in[3];
  const float* bhh0 = (const float*)d_in[4];
  const float* Wih1 = (const float*)d_in[5];
  const float* Whh1 = (const float*)d_in[6];
  const float* bih1 = (const float*)d_in[7];
  const float* bhh1 = (const float*)d_in[8];

  unsigned long long* fastb = (unsigned long long*)d_ws;
  unsigned long long* slowb;
  unsigned *ctrl, *flagF, *flagS;
  if (ws_size >= (1u << 20) + 12288u) {
    slowb = fastb + 65536;                      // @512KB
    ctrl  = (unsigned*)(fastb + 131072);        // @1MB   (272 u32 used)
    flagF = ctrl + 512;                         // @1MB+2KB (1024 u32)
    flagS = flagF + 1024;                       // @1MB+6KB (1024 u32)
  } else {                                      // compact fallback (uniform path unaffected)
    slowb = fastb;
    ctrl  = (unsigned*)((char*)d_ws + (512u << 10));
    flagF = ctrl + 512;
    flagS = flagF;
  }

  lstm2_v7<<<256, 256, 0, stream>>>(x, Wih0, Whh0, bih0, bhh0,
                                    Wih1, Whh1, bih1, bhh1,
                                    (float*)d_out, fastb, slowb, ctrl, flagF, flagS);
}